// Round 1
// baseline (322.907 us; speedup 1.0000x reference)
//
#include <hip/hip_runtime.h>
#include <hip/hip_cooperative_groups.h>

namespace cg = cooperative_groups;

#define D 2048
#define M 512

// Tuned NS coefficients, equioscillation on sv interval [0.48,1.52]:
// step1 -> delta 0.2188, step2 -> 0.03633, step3 -> 0.00099
#define CA1 1.7509363f
#define CB1 0.5353890f
#define CA2 1.5424421f
#define CB2 0.5060067f
#define CA3 1.5011558f
#define CB3 0.5001653f

typedef unsigned short u16;
typedef unsigned int u32;
typedef __attribute__((ext_vector_type(8))) short bf16x8;
typedef __attribute__((ext_vector_type(4))) float f32x4;

__device__ inline u16 f2bf(float f) {
    union { float f; unsigned u; } v; v.f = f;
    unsigned r = v.u + 0x7fffu + ((v.u >> 16) & 1u);  // RNE
    return (u16)(r >> 16);
}
__device__ inline float bf2f(u16 h) {
    union { float f; unsigned u; } v; v.u = ((unsigned)h) << 16;
    return v.f;
}

__device__ inline void store_split(u16* __restrict__ H, u16* __restrict__ L,
                                   size_t idx, float v) {
    const u16 h = f2bf(v);
    H[idx] = h;
    L[idx] = f2bf(v - bf2f(h));
}

// per-wave K-range fragment MACs into acc pair (split-bf16 3-MFMA scheme)
__device__ inline void mm_ks(const u16* __restrict__ aHi,
                             const u16* __restrict__ aLo, int lda,
                             const u16* __restrict__ bHi,
                             const u16* __restrict__ bLo, int ldb,
                             int K, int lm, int lq, f32x4& a1, f32x4& a2) {
    const u16* ah = aHi + (size_t)lm * lda + lq * 8;
    const u16* al = aLo + (size_t)lm * lda + lq * 8;
    const u16* bh = bHi + (size_t)lm * ldb + lq * 8;
    const u16* bl = bLo + (size_t)lm * ldb + lq * 8;
    #pragma unroll 8
    for (int k = 0; k < K; k += 32) {
        const bf16x8 fah = *(const bf16x8*)(ah + k);
        const bf16x8 fal = *(const bf16x8*)(al + k);
        const bf16x8 fbh = *(const bf16x8*)(bh + k);
        const bf16x8 fbl = *(const bf16x8*)(bl + k);
        a1 = __builtin_amdgcn_mfma_f32_16x16x32_bf16(fah, fbh, a1, 0, 0, 0);
        a2 = __builtin_amdgcn_mfma_f32_16x16x32_bf16(fah, fbl, a2, 0, 0, 0);
        a2 = __builtin_amdgcn_mfma_f32_16x16x32_bf16(fal, fbh, a2, 0, 0, 0);
    }
}

// 32x32 tile of U·V^T per 512-thread block: 8 waves = 4 quadrants x 2 K-halves.
__device__ inline void tile32(const u16* __restrict__ Uh, const u16* __restrict__ Ul, int lda,
                              const u16* __restrict__ Vh, const u16* __restrict__ Vl, int ldb,
                              int K, int i0, int j0, int t, float* red,
                              float val[2], int row[2], int col[2]) {
    const int w = t >> 6, lane = t & 63;
    const int lm = lane & 15, lq = lane >> 4;
    const int q = w >> 1, kh = w & 1;
    const int qi = q >> 1, qj = q & 1;
    const int Kh = K >> 1;
    const size_t ko = (size_t)kh * Kh;
    f32x4 a1 = {0.f, 0.f, 0.f, 0.f}, a2 = {0.f, 0.f, 0.f, 0.f};
    mm_ks(Uh + (size_t)(i0 + 16 * qi) * lda + ko, Ul + (size_t)(i0 + 16 * qi) * lda + ko, lda,
          Vh + (size_t)(j0 + 16 * qj) * ldb + ko, Vl + (size_t)(j0 + 16 * qj) * ldb + ko, ldb,
          Kh, lm, lq, a1, a2);
    const f32x4 s = a1 + a2;
    #pragma unroll
    for (int r = 0; r < 4; ++r) red[w * 256 + (lq * 4 + r) * 16 + lm] = s[r];
    __syncthreads();
    #pragma unroll
    for (int e = 0; e < 2; ++e) {
        const int ee = t + e * 512;
        const int qq = ee >> 8, p = ee & 255;
        val[e] = red[qq * 512 + p] + red[qq * 512 + 256 + p];
        row[e] = i0 + 16 * (qq >> 1) + (p >> 4);
        col[e] = j0 + 16 * (qq & 1) + (p & 15);
    }
}

// ---- d0: pack X (fp32) once -> split bf16 row-major Xhi/Xlo [D][M] and
// transposed XThi/XTlo [M][D]. 256 blocks x 512 thr, 64x64 fp32 tile/block.
__global__ __launch_bounds__(512) void packx(
    const float* __restrict__ X,
    u16* __restrict__ Xhi, u16* __restrict__ Xlo,
    u16* __restrict__ XTh, u16* __restrict__ XTl) {
    __shared__ u32 P[64][65];
    const int r0 = ((int)blockIdx.x >> 3) * 64, c0 = ((int)blockIdx.x & 7) * 64;
    const int t = threadIdx.x;
    const int rr = t >> 4;          // 0..31
    const int c4 = (t & 15) * 4;    // 0..60
    #pragma unroll
    for (int h = 0; h < 2; ++h) {
        const int r = rr + h * 32;
        const float4 f = *(const float4*)(X + (size_t)(r0 + r) * M + c0 + c4);
        const float vf[4] = {f.x, f.y, f.z, f.w};
        u32 pk[4];
        #pragma unroll
        for (int e = 0; e < 4; ++e) {
            union { float f; u32 u; } u; u.f = vf[e];
            const u32 hu = u.u & 0xFFFF0000u;   // truncated hi
            union { float f; u32 u; } hf; hf.u = hu;
            pk[e] = hu | (u32)f2bf(vf[e] - hf.f);
            P[r][c4 + e] = pk[e];
        }
        uint2 hw, lw;
        hw.x = (pk[0] >> 16) | (pk[1] & 0xFFFF0000u);
        hw.y = (pk[2] >> 16) | (pk[3] & 0xFFFF0000u);
        lw.x = (pk[0] & 0xFFFFu) | (pk[1] << 16);
        lw.y = (pk[2] & 0xFFFFu) | (pk[3] << 16);
        *(uint2*)(Xhi + (size_t)(r0 + r) * M + c0 + c4) = hw;
        *(uint2*)(Xlo + (size_t)(r0 + r) * M + c0 + c4) = lw;
    }
    __syncthreads();
    #pragma unroll
    for (int h = 0; h < 2; ++h) {
        const int c = rr + h * 32;
        const int r4 = c4;
        const u32 p0 = P[r4 + 0][c], p1 = P[r4 + 1][c];
        const u32 p2 = P[r4 + 2][c], p3 = P[r4 + 3][c];
        uint2 hw, lw;
        hw.x = (p0 >> 16) | (p1 & 0xFFFF0000u);
        hw.y = (p2 >> 16) | (p3 & 0xFFFF0000u);
        lw.x = (p0 & 0xFFFFu) | (p1 << 16);
        lw.y = (p2 & 0xFFFFu) | (p3 << 16);
        *(uint2*)(XTh + (size_t)(c0 + c) * D + r0 + r4) = hw;
        *(uint2*)(XTl + (size_t)(c0 + c) * D + r0 + r4) = lw;
    }
}

// ---- fused gram + full M-space chain, one cooperative launch.
// grid 256 x 512 thr; block b owns tile (b>>4, b&15) in every stage.
__global__ __launch_bounds__(512) void chain(
    const u16* __restrict__ XTh, const u16* __restrict__ XTl,
    u16* __restrict__ G0h, u16* __restrict__ G0l,
    u16* __restrict__ C1h, u16* __restrict__ C1l,
    u16* __restrict__ Sh,  u16* __restrict__ Sl,
    u16* __restrict__ G1h, u16* __restrict__ G1l,
    u16* __restrict__ C2h, u16* __restrict__ C2l,
    u16* __restrict__ S1h, u16* __restrict__ S1l,
    u16* __restrict__ B2h, u16* __restrict__ B2l,
    u16* __restrict__ C3h, u16* __restrict__ C3l,
    u16* __restrict__ B3h, u16* __restrict__ B3l) {
    __shared__ float red[2048];
    cg::grid_group grid = cg::this_grid();
    const int t = threadIdx.x;
    const int i0 = ((int)blockIdx.x >> 4) * 32, j0 = ((int)blockIdx.x & 15) * 32;
    float val[2]; int row[2], col[2];

    // s0: G0 = XT·XT^T (K = D); C1 = CA1·I - CB1·G0
    tile32(XTh, XTl, D, XTh, XTl, D, D, i0, j0, t, red, val, row, col);
    #pragma unroll
    for (int e = 0; e < 2; ++e) {
        const size_t idx = (size_t)row[e] * M + col[e];
        store_split(G0h, G0l, idx, val[e]);
        const float c = (row[e] == col[e] ? CA1 : 0.0f) - CB1 * val[e];
        store_split(C1h, C1l, idx, c);
    }
    grid.sync();

    // s1: S = G0·G0^T
    tile32(G0h, G0l, M, G0h, G0l, M, M, i0, j0, t, red, val, row, col);
    #pragma unroll
    for (int e = 0; e < 2; ++e) {
        const size_t idx = (size_t)row[e] * M + col[e];
        store_split(Sh, Sl, idx, val[e]);
    }
    grid.sync();

    // s2: W = G0·S^T; G1 = CA1^2 G0 - 2 CA1 CB1 S + CB1^2 W; C2 = CA2 I - CB2 G1
    tile32(G0h, G0l, M, Sh, Sl, M, M, i0, j0, t, red, val, row, col);
    #pragma unroll
    for (int e = 0; e < 2; ++e) {
        const size_t idx = (size_t)row[e] * M + col[e];
        const float p = (CA1 * CA1) * (bf2f(G0h[idx]) + bf2f(G0l[idx]))
                      + (-2.0f * CA1 * CB1) * (bf2f(Sh[idx]) + bf2f(Sl[idx]))
                      + (CB1 * CB1) * val[e];
        store_split(G1h, G1l, idx, p);
        const float c = (row[e] == col[e] ? CA2 : 0.0f) - CB2 * p;
        store_split(C2h, C2l, idx, c);
    }
    grid.sync();

    // s3: S1 = G1·G1^T ; then B2 = C1·C2^T
    tile32(G1h, G1l, M, G1h, G1l, M, M, i0, j0, t, red, val, row, col);
    #pragma unroll
    for (int e = 0; e < 2; ++e) {
        const size_t idx = (size_t)row[e] * M + col[e];
        store_split(S1h, S1l, idx, val[e]);
    }
    __syncthreads();
    tile32(C1h, C1l, M, C2h, C2l, M, M, i0, j0, t, red, val, row, col);
    #pragma unroll
    for (int e = 0; e < 2; ++e) {
        const size_t idx = (size_t)row[e] * M + col[e];
        store_split(B2h, B2l, idx, val[e]);
    }
    grid.sync();

    // s4: W1 = G1·S1^T; C3 = CA3 I - CB3 (CA2^2 G1 - 2 CA2 CB2 S1 + CB2^2 W1)
    tile32(G1h, G1l, M, S1h, S1l, M, M, i0, j0, t, red, val, row, col);
    #pragma unroll
    for (int e = 0; e < 2; ++e) {
        const size_t idx = (size_t)row[e] * M + col[e];
        const float p = (CA2 * CA2) * (bf2f(G1h[idx]) + bf2f(G1l[idx]))
                      + (-2.0f * CA2 * CB2) * (bf2f(S1h[idx]) + bf2f(S1l[idx]))
                      + (CB2 * CB2) * val[e];
        const float c = (row[e] == col[e] ? CA3 : 0.0f) - CB3 * p;
        store_split(C3h, C3l, idx, c);
    }
    grid.sync();

    // s5: B3 = B2·C3^T
    tile32(B2h, B2l, M, C3h, C3l, M, M, i0, j0, t, red, val, row, col);
    #pragma unroll
    for (int e = 0; e < 2; ++e) {
        const size_t idx = (size_t)row[e] * M + col[e];
        store_split(B3h, B3l, idx, val[e]);
    }
}

// ---- d7: out = X·B (fp32). 32x32 tile/block, 4 full-K quadrant waves.
__global__ __launch_bounds__(256) void final32(
    const u16* __restrict__ Xhi, const u16* __restrict__ Xlo,
    const u16* __restrict__ Bh, const u16* __restrict__ Bl,
    float* __restrict__ out) {
    const int t = threadIdx.x;
    const int i0 = ((int)blockIdx.x >> 4) * 32, j0 = ((int)blockIdx.x & 15) * 32;
    const int w = t >> 6, lane = t & 63;
    const int lm = lane & 15, lq = lane >> 4;
    const int qi = w >> 1, qj = w & 1;
    f32x4 a1 = {0.f, 0.f, 0.f, 0.f}, a2 = {0.f, 0.f, 0.f, 0.f};
    mm_ks(Xhi + (size_t)(i0 + 16 * qi) * M, Xlo + (size_t)(i0 + 16 * qi) * M, M,
          Bh + (size_t)(j0 + 16 * qj) * M, Bl + (size_t)(j0 + 16 * qj) * M, M,
          512, lm, lq, a1, a2);
    const f32x4 acc = a1 + a2;
    float* o = out + (size_t)(i0 + 16 * qi + lq * 4) * M + j0 + 16 * qj + lm;
    #pragma unroll
    for (int r = 0; r < 4; ++r) o[(size_t)r * M] = acc[r];
}

extern "C" void kernel_launch(void* const* d_in, const int* in_sizes, int n_in,
                              void* d_out, int out_size, void* d_ws, size_t ws_size,
                              hipStream_t stream) {
    const float* Xin = (const float*)d_in[0];
    float* out = (float*)d_out;
    u16* w = (u16*)d_ws;

    u16* Xhi = w;                      // D*M = 1048576 u16 each
    u16* Xlo = w + 1048576u;
    u16* XTh = w + 2097152u;
    u16* XTl = w + 3145728u;
    u16* q = w + 4194304u;             // M*M = 262144 u16 each below
    u16* G0h = q;            u16* G0l = q + 262144u;
    u16* C1h = q + 524288u;  u16* C1l = q + 786432u;
    u16* Sh  = q + 1048576u; u16* Sl  = q + 1310720u;
    u16* G1h = q + 1572864u; u16* G1l = q + 1835008u;
    u16* C2h = q + 2097152u; u16* C2l = q + 2359296u;
    u16* S1h = q + 2621440u; u16* S1l = q + 2883584u;
    u16* B2h = q + 3145728u; u16* B2l = q + 3407872u;
    u16* C3h = q + 3670016u; u16* C3l = q + 3932160u;
    u16* B3h = q + 4194304u; u16* B3l = q + 4456448u;

    // d0: one-time pack/split/transpose of X
    packx<<<256, 512, 0, stream>>>(Xin, Xhi, Xlo, XTh, XTl);

    // d1: fused gram + M-space chain (cooperative, 5 grid syncs)
    void* args[] = {
        (void*)&XTh, (void*)&XTl,
        (void*)&G0h, (void*)&G0l, (void*)&C1h, (void*)&C1l,
        (void*)&Sh,  (void*)&Sl,  (void*)&G1h, (void*)&G1l,
        (void*)&C2h, (void*)&C2l, (void*)&S1h, (void*)&S1l,
        (void*)&B2h, (void*)&B2l, (void*)&C3h, (void*)&C3l,
        (void*)&B3h, (void*)&B3l};
    hipLaunchCooperativeKernel((void*)chain, dim3(256), dim3(512), args, 0, stream);

    // d2: out = X·B3
    final32<<<1024, 256, 0, stream>>>(Xhi, Xlo, B3h, B3l, out);
}

// Round 2
// 171.592 us; speedup vs baseline: 1.8818x; 1.8818x over previous
//
#include <hip/hip_runtime.h>

#define D 2048
#define M 512

// Tuned NS coefficients, equioscillation on sv interval [0.48,1.52]:
// step1 -> delta 0.2188, step2 -> 0.03633, step3 -> 0.00099
#define CA1 1.7509363f
#define CB1 0.5353890f
#define CA2 1.5424421f
#define CB2 0.5060067f
#define CA3 1.5011558f
#define CB3 0.5001653f

typedef unsigned short u16;
typedef unsigned int u32;
typedef __attribute__((ext_vector_type(8))) short bf16x8;
typedef __attribute__((ext_vector_type(4))) float f32x4;

__device__ inline u16 f2bf(float f) {
    union { float f; unsigned u; } v; v.f = f;
    unsigned r = v.u + 0x7fffu + ((v.u >> 16) & 1u);  // RNE
    return (u16)(r >> 16);
}
__device__ inline float bf2f(u16 h) {
    union { float f; unsigned u; } v; v.u = ((unsigned)h) << 16;
    return v.f;
}

__device__ inline void store_split(u16* __restrict__ H, u16* __restrict__ L,
                                   size_t idx, float v) {
    const u16 h = f2bf(v);
    H[idx] = h;
    L[idx] = f2bf(v - bf2f(h));
}

// per-wave K-range fragment MACs into acc pair (split-bf16 3-MFMA scheme)
__device__ inline void mm_ks(const u16* __restrict__ aHi,
                             const u16* __restrict__ aLo, int lda,
                             const u16* __restrict__ bHi,
                             const u16* __restrict__ bLo, int ldb,
                             int K, int lm, int lq, f32x4& a1, f32x4& a2) {
    const u16* ah = aHi + (size_t)lm * lda + lq * 8;
    const u16* al = aLo + (size_t)lm * lda + lq * 8;
    const u16* bh = bHi + (size_t)lm * ldb + lq * 8;
    const u16* bl = bLo + (size_t)lm * ldb + lq * 8;
    #pragma unroll 8
    for (int k = 0; k < K; k += 32) {
        const bf16x8 fah = *(const bf16x8*)(ah + k);
        const bf16x8 fal = *(const bf16x8*)(al + k);
        const bf16x8 fbh = *(const bf16x8*)(bh + k);
        const bf16x8 fbl = *(const bf16x8*)(bl + k);
        a1 = __builtin_amdgcn_mfma_f32_16x16x32_bf16(fah, fbh, a1, 0, 0, 0);
        a2 = __builtin_amdgcn_mfma_f32_16x16x32_bf16(fah, fbl, a2, 0, 0, 0);
        a2 = __builtin_amdgcn_mfma_f32_16x16x32_bf16(fal, fbh, a2, 0, 0, 0);
    }
}

// 32x32 tile of U·V^T per 512-thread block: 8 waves = 4 quadrants x 2 K-halves.
__device__ inline void tile32(const u16* __restrict__ Uh, const u16* __restrict__ Ul, int lda,
                              const u16* __restrict__ Vh, const u16* __restrict__ Vl, int ldb,
                              int K, int i0, int j0, int t, float* red,
                              float val[2], int row[2], int col[2]) {
    const int w = t >> 6, lane = t & 63;
    const int lm = lane & 15, lq = lane >> 4;
    const int q = w >> 1, kh = w & 1;
    const int qi = q >> 1, qj = q & 1;
    const int Kh = K >> 1;
    const size_t ko = (size_t)kh * Kh;
    f32x4 a1 = {0.f, 0.f, 0.f, 0.f}, a2 = {0.f, 0.f, 0.f, 0.f};
    mm_ks(Uh + (size_t)(i0 + 16 * qi) * lda + ko, Ul + (size_t)(i0 + 16 * qi) * lda + ko, lda,
          Vh + (size_t)(j0 + 16 * qj) * ldb + ko, Vl + (size_t)(j0 + 16 * qj) * ldb + ko, ldb,
          Kh, lm, lq, a1, a2);
    const f32x4 s = a1 + a2;
    #pragma unroll
    for (int r = 0; r < 4; ++r) red[w * 256 + (lq * 4 + r) * 16 + lm] = s[r];
    __syncthreads();
    #pragma unroll
    for (int e = 0; e < 2; ++e) {
        const int ee = t + e * 512;
        const int qq = ee >> 8, p = ee & 255;
        val[e] = red[qq * 512 + p] + red[qq * 512 + 256 + p];
        row[e] = i0 + 16 * (qq >> 1) + (p >> 4);
        col[e] = j0 + 16 * (qq & 1) + (p & 15);
    }
}

// ---- d0: pack X (fp32) once -> split bf16 row-major Xhi/Xlo [D][M] and
// transposed XThi/XTlo [M][D]. 256 blocks x 512 thr, 64x64 fp32 tile/block.
__global__ __launch_bounds__(512) void packx(
    const float* __restrict__ X,
    u16* __restrict__ Xhi, u16* __restrict__ Xlo,
    u16* __restrict__ XTh, u16* __restrict__ XTl) {
    __shared__ u32 P[64][65];
    const int r0 = ((int)blockIdx.x >> 3) * 64, c0 = ((int)blockIdx.x & 7) * 64;
    const int t = threadIdx.x;
    const int rr = t >> 4;          // 0..31
    const int c4 = (t & 15) * 4;    // 0..60
    #pragma unroll
    for (int h = 0; h < 2; ++h) {
        const int r = rr + h * 32;
        const float4 f = *(const float4*)(X + (size_t)(r0 + r) * M + c0 + c4);
        const float vf[4] = {f.x, f.y, f.z, f.w};
        u32 pk[4];
        #pragma unroll
        for (int e = 0; e < 4; ++e) {
            union { float f; u32 u; } u; u.f = vf[e];
            const u32 hu = u.u & 0xFFFF0000u;   // truncated hi
            union { float f; u32 u; } hf; hf.u = hu;
            pk[e] = hu | (u32)f2bf(vf[e] - hf.f);
            P[r][c4 + e] = pk[e];
        }
        uint2 hw, lw;
        hw.x = (pk[0] >> 16) | (pk[1] & 0xFFFF0000u);
        hw.y = (pk[2] >> 16) | (pk[3] & 0xFFFF0000u);
        lw.x = (pk[0] & 0xFFFFu) | (pk[1] << 16);
        lw.y = (pk[2] & 0xFFFFu) | (pk[3] << 16);
        *(uint2*)(Xhi + (size_t)(r0 + r) * M + c0 + c4) = hw;
        *(uint2*)(Xlo + (size_t)(r0 + r) * M + c0 + c4) = lw;
    }
    __syncthreads();
    #pragma unroll
    for (int h = 0; h < 2; ++h) {
        const int c = rr + h * 32;
        const int r4 = c4;
        const u32 p0 = P[r4 + 0][c], p1 = P[r4 + 1][c];
        const u32 p2 = P[r4 + 2][c], p3 = P[r4 + 3][c];
        uint2 hw, lw;
        hw.x = (p0 >> 16) | (p1 & 0xFFFF0000u);
        hw.y = (p2 >> 16) | (p3 & 0xFFFF0000u);
        lw.x = (p0 & 0xFFFFu) | (p1 << 16);
        lw.y = (p2 & 0xFFFFu) | (p3 << 16);
        *(uint2*)(XTh + (size_t)(c0 + c) * D + r0 + r4) = hw;
        *(uint2*)(XTl + (size_t)(c0 + c) * D + r0 + r4) = lw;
    }
}

// ---- d1: G0 = XT·XT^T from pre-packed XT, C1 = CA1 I - CB1 G0.
// 16x32 tile/block, 512 blocks x 512 thr: 8 waves = 2 col-quadrants x 4 K-quarters.
// 2 blocks/CU, Kq=512 per wave -> half the serial load chain of a K-half scheme.
__global__ __launch_bounds__(512) void gramp(
    const u16* __restrict__ XTh, const u16* __restrict__ XTl,
    u16* __restrict__ Gh, u16* __restrict__ Gl,
    u16* __restrict__ Ch, u16* __restrict__ Cl) {
    __shared__ float red[2048];
    const int i0 = ((int)blockIdx.x >> 4) * 16;   // 32 i-tiles of 16 rows
    const int j0 = ((int)blockIdx.x & 15) * 32;   // 16 j-tiles of 32 cols
    const int t = threadIdx.x, w = t >> 6, lane = t & 63;
    const int lm = lane & 15, lq = lane >> 4;
    const int qj = w & 1, kq = w >> 1;            // col quadrant, K quarter
    const size_t ko = (size_t)kq * 512;
    f32x4 a1 = {0.f, 0.f, 0.f, 0.f}, a2 = {0.f, 0.f, 0.f, 0.f};
    mm_ks(XTh + (size_t)i0 * D + ko, XTl + (size_t)i0 * D + ko, D,
          XTh + (size_t)(j0 + 16 * qj) * D + ko,
          XTl + (size_t)(j0 + 16 * qj) * D + ko, D,
          512, lm, lq, a1, a2);
    const f32x4 s = a1 + a2;
    #pragma unroll
    for (int r = 0; r < 4; ++r) red[w * 256 + (lq * 4 + r) * 16 + lm] = s[r];
    __syncthreads();
    const int qq = t >> 8, p = t & 255;           // one output elem per thread
    const float g = red[(0 + qq) * 256 + p] + red[(2 + qq) * 256 + p]
                  + red[(4 + qq) * 256 + p] + red[(6 + qq) * 256 + p];
    const int row = i0 + (p >> 4), col = j0 + 16 * qq + (p & 15);
    const size_t idx = (size_t)row * M + col;
    store_split(Gh, Gl, idx, g);
    const float c = (row == col ? CA1 : 0.0f) - CB1 * g;
    store_split(Ch, Cl, idx, c);
}

// ---- plain M-space mm: O = U·V^T. grid 256 x 512 thr, 32x32 tile/block.
__global__ __launch_bounds__(512) void mm32(
    const u16* __restrict__ Uh, const u16* __restrict__ Ul,
    const u16* __restrict__ Vh, const u16* __restrict__ Vl,
    u16* __restrict__ Oh, u16* __restrict__ Ol) {
    __shared__ float red[2048];
    const int i0 = ((int)blockIdx.x >> 4) * 32, j0 = ((int)blockIdx.x & 15) * 32;
    float val[2]; int row[2], col[2];
    tile32(Uh, Ul, M, Vh, Vl, M, 512, i0, j0, threadIdx.x, red, val, row, col);
    #pragma unroll
    for (int e = 0; e < 2; ++e) {
        const size_t idx = (size_t)row[e] * M + col[e];
        store_split(Oh, Ol, idx, val[e]);
    }
}

// ---- dual M-space mm: job0: O0=U0·V0^T, job1: O1=U1·V1^T. grid 512 x 512 thr.
__global__ __launch_bounds__(512) void dual32(
    const u16* __restrict__ U0h, const u16* __restrict__ U0l,
    const u16* __restrict__ V0h, const u16* __restrict__ V0l,
    u16* __restrict__ O0h, u16* __restrict__ O0l,
    const u16* __restrict__ U1h, const u16* __restrict__ U1l,
    const u16* __restrict__ V1h, const u16* __restrict__ V1l,
    u16* __restrict__ O1h, u16* __restrict__ O1l) {
    __shared__ float red[2048];
    const int job = (int)blockIdx.x >> 8, tile = (int)blockIdx.x & 255;
    const int i0 = (tile >> 4) * 32, j0 = (tile & 15) * 32;
    const u16* Uh = job ? U1h : U0h;
    const u16* Ul = job ? U1l : U0l;
    const u16* Vh = job ? V1h : V0h;
    const u16* Vl = job ? V1l : V0l;
    u16* Oh = job ? O1h : O0h;
    u16* Ol = job ? O1l : O0l;
    float val[2]; int row[2], col[2];
    tile32(Uh, Ul, M, Vh, Vl, M, 512, i0, j0, threadIdx.x, red, val, row, col);
    #pragma unroll
    for (int e = 0; e < 2; ++e) {
        const size_t idx = (size_t)row[e] * M + col[e];
        store_split(Oh, Ol, idx, val[e]);
    }
}

// ---- poly step: W=U·V^T; P = cA*Ge + cB*Se + cC*W; store P (opt), C = a*I - b*P.
__global__ __launch_bounds__(512) void poly32(
    const u16* __restrict__ Uh, const u16* __restrict__ Ul,
    const u16* __restrict__ Vh, const u16* __restrict__ Vl,
    const u16* __restrict__ Geh, const u16* __restrict__ Gel,
    const u16* __restrict__ Seh, const u16* __restrict__ Sel,
    u16* __restrict__ Ph, u16* __restrict__ Pl,
    u16* __restrict__ Ch, u16* __restrict__ Cl,
    const float cA, const float cB, const float cC,
    const float a, const float b, const int writeP) {
    __shared__ float red[2048];
    const int i0 = ((int)blockIdx.x >> 4) * 32, j0 = ((int)blockIdx.x & 15) * 32;
    float val[2]; int row[2], col[2];
    tile32(Uh, Ul, M, Vh, Vl, M, 512, i0, j0, threadIdx.x, red, val, row, col);
    #pragma unroll
    for (int e = 0; e < 2; ++e) {
        const size_t idx = (size_t)row[e] * M + col[e];
        const float p = cA * (bf2f(Geh[idx]) + bf2f(Gel[idx]))
                      + cB * (bf2f(Seh[idx]) + bf2f(Sel[idx]))
                      + cC * val[e];
        if (writeP) {
            store_split(Ph, Pl, idx, p);
        }
        const float c = (row[e] == col[e] ? a : 0.0f) - b * p;
        store_split(Ch, Cl, idx, c);
    }
}

// ---- d7: out = X·B^T (fp32 out). tile32 path: 1024 blocks x 512 thr,
// 2 blocks/CU, K-half per wave (32 load batches -> 16).
__global__ __launch_bounds__(512) void xb32(
    const u16* __restrict__ Xhi, const u16* __restrict__ Xlo,
    const u16* __restrict__ Bh, const u16* __restrict__ Bl,
    float* __restrict__ out) {
    __shared__ float red[2048];
    const int i0 = ((int)blockIdx.x >> 4) * 32, j0 = ((int)blockIdx.x & 15) * 32;
    float val[2]; int row[2], col[2];
    tile32(Xhi, Xlo, M, Bh, Bl, M, 512, i0, j0, threadIdx.x, red, val, row, col);
    #pragma unroll
    for (int e = 0; e < 2; ++e)
        out[(size_t)row[e] * M + col[e]] = val[e];
}

extern "C" void kernel_launch(void* const* d_in, const int* in_sizes, int n_in,
                              void* d_out, int out_size, void* d_ws, size_t ws_size,
                              hipStream_t stream) {
    const float* Xin = (const float*)d_in[0];
    float* out = (float*)d_out;
    u16* w = (u16*)d_ws;

    u16* Xhi = w;                      // D*M = 1048576 u16 each
    u16* Xlo = w + 1048576u;
    u16* XTh = w + 2097152u;
    u16* XTl = w + 3145728u;
    u16* q = w + 4194304u;             // M*M = 262144 u16 each below
    u16* G0h = q;            u16* G0l = q + 262144u;
    u16* C1h = q + 524288u;  u16* C1l = q + 786432u;
    u16* Sh  = q + 1048576u; u16* Sl  = q + 1310720u;
    u16* G1h = q + 1572864u; u16* G1l = q + 1835008u;
    u16* C2h = q + 2097152u; u16* C2l = q + 2359296u;
    u16* S1h = q + 2621440u; u16* S1l = q + 2883584u;
    u16* B2h = q + 3145728u; u16* B2l = q + 3407872u;
    u16* C3h = q + 3670016u; u16* C3l = q + 3932160u;
    u16* B3h = q + 4194304u; u16* B3l = q + 4456448u;

    // d0: one-time pack/split/transpose of X
    packx<<<256, 512, 0, stream>>>(Xin, Xhi, Xlo, XTh, XTl);
    // d1: G0 = X^T X from packed XT; C1 = CA1 I - CB1 G0
    gramp<<<512, 512, 0, stream>>>(XTh, XTl, G0h, G0l, C1h, C1l);
    // d2: S = G0^2
    mm32<<<256, 512, 0, stream>>>(G0h, G0l, G0h, G0l, Sh, Sl);
    // d3: G1 = CA1^2 G0 - 2 CA1 CB1 S + CB1^2 (G0·S) ; C2 = CA2 I - CB2 G1
    poly32<<<256, 512, 0, stream>>>(G0h, G0l, Sh, Sl, G0h, G0l, Sh, Sl,
                                    G1h, G1l, C2h, C2l,
                                    CA1 * CA1, -2.0f * CA1 * CB1, CB1 * CB1,
                                    CA2, CB2, 1);
    // d4: S1 = G1^2  ||  B2 = C1·C2
    dual32<<<512, 512, 0, stream>>>(G1h, G1l, G1h, G1l, S1h, S1l,
                                    C1h, C1l, C2h, C2l, B2h, B2l);
    // d5: G2-poly -> C3 only
    poly32<<<256, 512, 0, stream>>>(G1h, G1l, S1h, S1l, G1h, G1l, S1h, S1l,
                                    nullptr, nullptr, C3h, C3l,
                                    CA2 * CA2, -2.0f * CA2 * CB2, CB2 * CB2,
                                    CA3, CB3, 0);
    // d6: B3 = B2·C3
    mm32<<<256, 512, 0, stream>>>(B2h, B2l, C3h, C3l, B3h, B3l);
    // d7: out = X·B3
    xb32<<<1024, 512, 0, stream>>>(Xhi, Xlo, B3h, B3l, out);
}

// Round 3
// 171.253 us; speedup vs baseline: 1.8856x; 1.0020x over previous
//
#include <hip/hip_runtime.h>

#define D 2048
#define M 512

// Tuned NS coefficients, equioscillation on sv interval [0.48,1.52]:
// step1 -> delta 0.2188, step2 -> 0.03633, step3 -> 0.00099
#define CA1 1.7509363f
#define CB1 0.5353890f
#define CA2 1.5424421f
#define CB2 0.5060067f
#define CA3 1.5011558f
#define CB3 0.5001653f

typedef unsigned short u16;
typedef unsigned int u32;
typedef __attribute__((ext_vector_type(8))) short bf16x8;
typedef __attribute__((ext_vector_type(4))) float f32x4;

__device__ inline u16 f2bf(float f) {
    union { float f; unsigned u; } v; v.f = f;
    unsigned r = v.u + 0x7fffu + ((v.u >> 16) & 1u);  // RNE
    return (u16)(r >> 16);
}
__device__ inline float bf2f(u16 h) {
    union { float f; unsigned u; } v; v.u = ((unsigned)h) << 16;
    return v.f;
}

__device__ inline void store_split(u16* __restrict__ H, u16* __restrict__ L,
                                   size_t idx, float v) {
    const u16 h = f2bf(v);
    H[idx] = h;
    L[idx] = f2bf(v - bf2f(h));
}

// One 128-k chunk: explicitly load all 16 fragments (64 VGPRs) FIRST, then
// issue 12 MFMAs. Forces a single latency epoch per chunk instead of one
// per k-iteration (the VGPR=52 codegen kept only ~3 loads in flight).
// MFMA sequence per k is identical to the old loop -> bit-identical sums.
__device__ inline void mmchunk(const u16* __restrict__ ah, const u16* __restrict__ al,
                               const u16* __restrict__ bh, const u16* __restrict__ bl,
                               f32x4& a1, f32x4& a2) {
    bf16x8 fah[4], fal[4], fbh[4], fbl[4];
    #pragma unroll
    for (int i = 0; i < 4; ++i) {
        fah[i] = *(const bf16x8*)(ah + 32 * i);
        fal[i] = *(const bf16x8*)(al + 32 * i);
        fbh[i] = *(const bf16x8*)(bh + 32 * i);
        fbl[i] = *(const bf16x8*)(bl + 32 * i);
    }
    #pragma unroll
    for (int i = 0; i < 4; ++i) {
        a1 = __builtin_amdgcn_mfma_f32_16x16x32_bf16(fah[i], fbh[i], a1, 0, 0, 0);
        a2 = __builtin_amdgcn_mfma_f32_16x16x32_bf16(fah[i], fbl[i], a2, 0, 0, 0);
        a2 = __builtin_amdgcn_mfma_f32_16x16x32_bf16(fal[i], fbh[i], a2, 0, 0, 0);
    }
}

// per-wave K-range fragment MACs (K multiple of 128)
__device__ inline void mm_ks(const u16* __restrict__ aHi,
                             const u16* __restrict__ aLo, int lda,
                             const u16* __restrict__ bHi,
                             const u16* __restrict__ bLo, int ldb,
                             int K, int lm, int lq, f32x4& a1, f32x4& a2) {
    const u16* ah = aHi + (size_t)lm * lda + lq * 8;
    const u16* al = aLo + (size_t)lm * lda + lq * 8;
    const u16* bh = bHi + (size_t)lm * ldb + lq * 8;
    const u16* bl = bLo + (size_t)lm * ldb + lq * 8;
    #pragma unroll 4
    for (int k = 0; k < K; k += 128)
        mmchunk(ah + k, al + k, bh + k, bl + k, a1, a2);
}

// 16x32 tile of U·V^T per 512-thread block, K=512 fixed, 4-way K-split:
// 8 waves = 2 col-quadrants x 4 K-quarters, Kq=128 = exactly one chunk/wave.
__device__ inline void tile16(const u16* __restrict__ Uh, const u16* __restrict__ Ul, int lda,
                              const u16* __restrict__ Vh, const u16* __restrict__ Vl, int ldb,
                              int i0, int j0, int t, float* red,
                              float& val, int& row, int& col) {
    const int w = t >> 6, lane = t & 63;
    const int lm = lane & 15, lq = lane >> 4;
    const int qj = w & 1, kq = w >> 1;
    const size_t ko = (size_t)kq * 128;
    f32x4 a1 = {0.f, 0.f, 0.f, 0.f}, a2 = {0.f, 0.f, 0.f, 0.f};
    const u16* ah = Uh + (size_t)(i0 + lm) * lda + ko + lq * 8;
    const u16* al = Ul + (size_t)(i0 + lm) * lda + ko + lq * 8;
    const u16* bh = Vh + (size_t)(j0 + 16 * qj + lm) * ldb + ko + lq * 8;
    const u16* bl = Vl + (size_t)(j0 + 16 * qj + lm) * ldb + ko + lq * 8;
    mmchunk(ah, al, bh, bl, a1, a2);
    const f32x4 s = a1 + a2;
    #pragma unroll
    for (int r = 0; r < 4; ++r) red[w * 256 + (lq * 4 + r) * 16 + lm] = s[r];
    __syncthreads();
    const int qq = t >> 8, p = t & 255;
    val = red[(0 + qq) * 256 + p] + red[(2 + qq) * 256 + p]
        + red[(4 + qq) * 256 + p] + red[(6 + qq) * 256 + p];
    row = i0 + (p >> 4);
    col = j0 + 16 * qq + (p & 15);
}

// ---- d0: pack X (fp32) once -> split bf16 row-major Xhi/Xlo [D][M] and
// transposed XThi/XTlo [M][D]. 256 blocks x 512 thr, 64x64 fp32 tile/block.
__global__ __launch_bounds__(512) void packx(
    const float* __restrict__ X,
    u16* __restrict__ Xhi, u16* __restrict__ Xlo,
    u16* __restrict__ XTh, u16* __restrict__ XTl) {
    __shared__ u32 P[64][65];
    const int r0 = ((int)blockIdx.x >> 3) * 64, c0 = ((int)blockIdx.x & 7) * 64;
    const int t = threadIdx.x;
    const int rr = t >> 4;          // 0..31
    const int c4 = (t & 15) * 4;    // 0..60
    #pragma unroll
    for (int h = 0; h < 2; ++h) {
        const int r = rr + h * 32;
        const float4 f = *(const float4*)(X + (size_t)(r0 + r) * M + c0 + c4);
        const float vf[4] = {f.x, f.y, f.z, f.w};
        u32 pk[4];
        #pragma unroll
        for (int e = 0; e < 4; ++e) {
            union { float f; u32 u; } u; u.f = vf[e];
            const u32 hu = u.u & 0xFFFF0000u;   // truncated hi
            union { float f; u32 u; } hf; hf.u = hu;
            pk[e] = hu | (u32)f2bf(vf[e] - hf.f);
            P[r][c4 + e] = pk[e];
        }
        uint2 hw, lw;
        hw.x = (pk[0] >> 16) | (pk[1] & 0xFFFF0000u);
        hw.y = (pk[2] >> 16) | (pk[3] & 0xFFFF0000u);
        lw.x = (pk[0] & 0xFFFFu) | (pk[1] << 16);
        lw.y = (pk[2] & 0xFFFFu) | (pk[3] << 16);
        *(uint2*)(Xhi + (size_t)(r0 + r) * M + c0 + c4) = hw;
        *(uint2*)(Xlo + (size_t)(r0 + r) * M + c0 + c4) = lw;
    }
    __syncthreads();
    #pragma unroll
    for (int h = 0; h < 2; ++h) {
        const int c = rr + h * 32;
        const int r4 = c4;
        const u32 p0 = P[r4 + 0][c], p1 = P[r4 + 1][c];
        const u32 p2 = P[r4 + 2][c], p3 = P[r4 + 3][c];
        uint2 hw, lw;
        hw.x = (p0 >> 16) | (p1 & 0xFFFF0000u);
        hw.y = (p2 >> 16) | (p3 & 0xFFFF0000u);
        lw.x = (p0 & 0xFFFFu) | (p1 << 16);
        lw.y = (p2 & 0xFFFFu) | (p3 << 16);
        *(uint2*)(XTh + (size_t)(c0 + c) * D + r0 + r4) = hw;
        *(uint2*)(XTl + (size_t)(c0 + c) * D + r0 + r4) = lw;
    }
}

// ---- d1: G0 = XT·XT^T from pre-packed XT, C1 = CA1 I - CB1 G0.
// 16x32 tile/block, 512 blocks x 512 thr, Kq=512 = 4 chunks/wave.
__global__ __launch_bounds__(512) void gramp(
    const u16* __restrict__ XTh, const u16* __restrict__ XTl,
    u16* __restrict__ Gh, u16* __restrict__ Gl,
    u16* __restrict__ Ch, u16* __restrict__ Cl) {
    __shared__ float red[2048];
    const int i0 = ((int)blockIdx.x >> 4) * 16;
    const int j0 = ((int)blockIdx.x & 15) * 32;
    const int t = threadIdx.x, w = t >> 6, lane = t & 63;
    const int lm = lane & 15, lq = lane >> 4;
    const int qj = w & 1, kq = w >> 1;
    const size_t ko = (size_t)kq * 512;
    f32x4 a1 = {0.f, 0.f, 0.f, 0.f}, a2 = {0.f, 0.f, 0.f, 0.f};
    mm_ks(XTh + (size_t)i0 * D + ko, XTl + (size_t)i0 * D + ko, D,
          XTh + (size_t)(j0 + 16 * qj) * D + ko,
          XTl + (size_t)(j0 + 16 * qj) * D + ko, D,
          512, lm, lq, a1, a2);
    const f32x4 s = a1 + a2;
    #pragma unroll
    for (int r = 0; r < 4; ++r) red[w * 256 + (lq * 4 + r) * 16 + lm] = s[r];
    __syncthreads();
    const int qq = t >> 8, p = t & 255;
    const float g = red[(0 + qq) * 256 + p] + red[(2 + qq) * 256 + p]
                  + red[(4 + qq) * 256 + p] + red[(6 + qq) * 256 + p];
    const int row = i0 + (p >> 4), col = j0 + 16 * qq + (p & 15);
    const size_t idx = (size_t)row * M + col;
    store_split(Gh, Gl, idx, g);
    const float c = (row == col ? CA1 : 0.0f) - CB1 * g;
    store_split(Ch, Cl, idx, c);
}

// ---- plain M-space mm: O = U·V^T. grid 512 x 512 thr, 16x32 tile/block.
__global__ __launch_bounds__(512) void mm32(
    const u16* __restrict__ Uh, const u16* __restrict__ Ul,
    const u16* __restrict__ Vh, const u16* __restrict__ Vl,
    u16* __restrict__ Oh, u16* __restrict__ Ol) {
    __shared__ float red[2048];
    const int i0 = ((int)blockIdx.x >> 4) * 16, j0 = ((int)blockIdx.x & 15) * 32;
    float val; int row, col;
    tile16(Uh, Ul, M, Vh, Vl, M, i0, j0, threadIdx.x, red, val, row, col);
    store_split(Oh, Ol, (size_t)row * M + col, val);
}

// ---- dual M-space mm: job0: O0=U0·V0^T, job1: O1=U1·V1^T. grid 1024 x 512 thr.
__global__ __launch_bounds__(512) void dual32(
    const u16* __restrict__ U0h, const u16* __restrict__ U0l,
    const u16* __restrict__ V0h, const u16* __restrict__ V0l,
    u16* __restrict__ O0h, u16* __restrict__ O0l,
    const u16* __restrict__ U1h, const u16* __restrict__ U1l,
    const u16* __restrict__ V1h, const u16* __restrict__ V1l,
    u16* __restrict__ O1h, u16* __restrict__ O1l) {
    __shared__ float red[2048];
    const int job = (int)blockIdx.x >> 9, tile = (int)blockIdx.x & 511;
    const int i0 = (tile >> 4) * 16, j0 = (tile & 15) * 32;
    const u16* Uh = job ? U1h : U0h;
    const u16* Ul = job ? U1l : U0l;
    const u16* Vh = job ? V1h : V0h;
    const u16* Vl = job ? V1l : V0l;
    u16* Oh = job ? O1h : O0h;
    u16* Ol = job ? O1l : O0l;
    float val; int row, col;
    tile16(Uh, Ul, M, Vh, Vl, M, i0, j0, threadIdx.x, red, val, row, col);
    store_split(Oh, Ol, (size_t)row * M + col, val);
}

// ---- poly step: W=U·V^T; P = cA*Ge + cB*Se + cC*W; store P (opt), C = a*I - b*P.
__global__ __launch_bounds__(512) void poly32(
    const u16* __restrict__ Uh, const u16* __restrict__ Ul,
    const u16* __restrict__ Vh, const u16* __restrict__ Vl,
    const u16* __restrict__ Geh, const u16* __restrict__ Gel,
    const u16* __restrict__ Seh, const u16* __restrict__ Sel,
    u16* __restrict__ Ph, u16* __restrict__ Pl,
    u16* __restrict__ Ch, u16* __restrict__ Cl,
    const float cA, const float cB, const float cC,
    const float a, const float b, const int writeP) {
    __shared__ float red[2048];
    const int i0 = ((int)blockIdx.x >> 4) * 16, j0 = ((int)blockIdx.x & 15) * 32;
    float val; int row, col;
    tile16(Uh, Ul, M, Vh, Vl, M, i0, j0, threadIdx.x, red, val, row, col);
    const size_t idx = (size_t)row * M + col;
    const float p = cA * (bf2f(Geh[idx]) + bf2f(Gel[idx]))
                  + cB * (bf2f(Seh[idx]) + bf2f(Sel[idx]))
                  + cC * val;
    if (writeP) {
        store_split(Ph, Pl, idx, p);
    }
    const float c = (row == col ? a : 0.0f) - b * p;
    store_split(Ch, Cl, idx, c);
}

// ---- d7: out = X·B^T (fp32 out). 32x32 tile, 1024 blocks x 512 thr,
// 8 waves = 4 quadrants x 2 K-halves, Kh=256 = 2 chunks/wave.
__global__ __launch_bounds__(512) void xb32(
    const u16* __restrict__ Xhi, const u16* __restrict__ Xlo,
    const u16* __restrict__ Bh, const u16* __restrict__ Bl,
    float* __restrict__ out) {
    __shared__ float red[2048];
    const int i0 = ((int)blockIdx.x >> 4) * 32, j0 = ((int)blockIdx.x & 15) * 32;
    const int t = threadIdx.x, w = t >> 6, lane = t & 63;
    const int lm = lane & 15, lq = lane >> 4;
    const int q = w >> 1, kh = w & 1;
    const int qi = q >> 1, qj = q & 1;
    const size_t ko = (size_t)kh * 256;
    f32x4 a1 = {0.f, 0.f, 0.f, 0.f}, a2 = {0.f, 0.f, 0.f, 0.f};
    mm_ks(Xhi + (size_t)(i0 + 16 * qi) * M + ko, Xlo + (size_t)(i0 + 16 * qi) * M + ko, M,
          Bh + (size_t)(j0 + 16 * qj) * M + ko, Bl + (size_t)(j0 + 16 * qj) * M + ko, M,
          256, lm, lq, a1, a2);
    const f32x4 s = a1 + a2;
    #pragma unroll
    for (int r = 0; r < 4; ++r) red[w * 256 + (lq * 4 + r) * 16 + lm] = s[r];
    __syncthreads();
    #pragma unroll
    for (int e = 0; e < 2; ++e) {
        const int ee = t + e * 512;
        const int qq = ee >> 8, p = ee & 255;
        const float v = red[qq * 512 + p] + red[qq * 512 + 256 + p];
        const int row = i0 + 16 * (qq >> 1) + (p >> 4);
        const int col = j0 + 16 * (qq & 1) + (p & 15);
        out[(size_t)row * M + col] = v;
    }
}

extern "C" void kernel_launch(void* const* d_in, const int* in_sizes, int n_in,
                              void* d_out, int out_size, void* d_ws, size_t ws_size,
                              hipStream_t stream) {
    const float* Xin = (const float*)d_in[0];
    float* out = (float*)d_out;
    u16* w = (u16*)d_ws;

    u16* Xhi = w;                      // D*M = 1048576 u16 each
    u16* Xlo = w + 1048576u;
    u16* XTh = w + 2097152u;
    u16* XTl = w + 3145728u;
    u16* q = w + 4194304u;             // M*M = 262144 u16 each below
    u16* G0h = q;            u16* G0l = q + 262144u;
    u16* C1h = q + 524288u;  u16* C1l = q + 786432u;
    u16* Sh  = q + 1048576u; u16* Sl  = q + 1310720u;
    u16* G1h = q + 1572864u; u16* G1l = q + 1835008u;
    u16* C2h = q + 2097152u; u16* C2l = q + 2359296u;
    u16* S1h = q + 2621440u; u16* S1l = q + 2883584u;
    u16* B2h = q + 3145728u; u16* B2l = q + 3407872u;
    u16* C3h = q + 3670016u; u16* C3l = q + 3932160u;
    u16* B3h = q + 4194304u; u16* B3l = q + 4456448u;

    // d0: one-time pack/split/transpose of X
    packx<<<256, 512, 0, stream>>>(Xin, Xhi, Xlo, XTh, XTl);
    // d1: G0 = X^T X from packed XT; C1 = CA1 I - CB1 G0
    gramp<<<512, 512, 0, stream>>>(XTh, XTl, G0h, G0l, C1h, C1l);
    // d2: S = G0^2
    mm32<<<512, 512, 0, stream>>>(G0h, G0l, G0h, G0l, Sh, Sl);
    // d3: G1 = CA1^2 G0 - 2 CA1 CB1 S + CB1^2 (G0·S) ; C2 = CA2 I - CB2 G1
    poly32<<<512, 512, 0, stream>>>(G0h, G0l, Sh, Sl, G0h, G0l, Sh, Sl,
                                    G1h, G1l, C2h, C2l,
                                    CA1 * CA1, -2.0f * CA1 * CB1, CB1 * CB1,
                                    CA2, CB2, 1);
    // d4: S1 = G1^2  ||  B2 = C1·C2
    dual32<<<1024, 512, 0, stream>>>(G1h, G1l, G1h, G1l, S1h, S1l,
                                     C1h, C1l, C2h, C2l, B2h, B2l);
    // d5: G2-poly -> C3 only
    poly32<<<512, 512, 0, stream>>>(G1h, G1l, S1h, S1l, G1h, G1l, S1h, S1l,
                                    nullptr, nullptr, C3h, C3l,
                                    CA2 * CA2, -2.0f * CA2 * CB2, CB2 * CB2,
                                    CA3, CB3, 0);
    // d6: B3 = B2·C3
    mm32<<<512, 512, 0, stream>>>(B2h, B2l, C3h, C3l, B3h, B3l);
    // d7: out = X·B3
    xb32<<<1024, 512, 0, stream>>>(Xhi, Xlo, B3h, B3l, out);
}